// Round 1
// baseline (310.675 us; speedup 1.0000x reference)
//
#include <hip/hip_runtime.h>

#define D 128

typedef __attribute__((ext_vector_type(8))) short short8;
typedef __attribute__((ext_vector_type(4))) float f32x4;

// fp32 -> bf16 bits, round-to-nearest-even
__device__ inline unsigned int f2bf_bits(float f) {
    unsigned int u = __float_as_uint(f);
    return (u + 0x7FFFu + ((u >> 16) & 1u)) >> 16;
}

__device__ inline float bfhi(unsigned int u) { return __uint_as_float(u << 16); }
__device__ inline float bflo(unsigned int u) { return __uint_as_float(u & 0xffff0000u); }

// ---------------- fused prep: x -> bf16 hi/lo (row-major), weight pack, zero chist/csrpad ----
__global__ __launch_bounds__(256) void prep_kernel(
    const float* __restrict__ x,
    const float* __restrict__ W1l, const float* __restrict__ W1r,
    const float* __restrict__ W2l, const float* __restrict__ W2r,
    unsigned short* __restrict__ xbf, unsigned short* __restrict__ xlo,
    unsigned short* __restrict__ h1, unsigned short* __restrict__ l1,
    unsigned short* __restrict__ h2, unsigned short* __restrict__ l2,
    int n4, int ncast, int* __restrict__ chist, int* __restrict__ csrpad)
{
    const int b = blockIdx.x;
    const int t = threadIdx.x;
    if (b < ncast) {
        int i = b * 256 + t;
        if (i >= n4) return;
        f32x4 v = *(const f32x4*)(x + (size_t)i * 4);
        ushort4 oh, ol;
        {
            unsigned int h; float hf;
            h = f2bf_bits(v.x); hf = __uint_as_float(h << 16);
            oh.x = (unsigned short)h; ol.x = (unsigned short)f2bf_bits(v.x - hf);
            h = f2bf_bits(v.y); hf = __uint_as_float(h << 16);
            oh.y = (unsigned short)h; ol.y = (unsigned short)f2bf_bits(v.y - hf);
            h = f2bf_bits(v.z); hf = __uint_as_float(h << 16);
            oh.z = (unsigned short)h; ol.z = (unsigned short)f2bf_bits(v.z - hf);
            h = f2bf_bits(v.w); hf = __uint_as_float(h << 16);
            oh.w = (unsigned short)h; ol.w = (unsigned short)f2bf_bits(v.w - hf);
        }
        *(ushort4*)(xbf + (size_t)i * 4) = oh;
        *(ushort4*)(xlo + (size_t)i * 4) = ol;
    } else if (b < ncast + 256) {
        // weight pack: B-frag order + bf16 hi/lo split
        int gidx = (b - ncast) * 256 + t;   // 0..65535
        int sel = gidx >> 15;
        int idx = gidx & 32767;
        int tt = idx >> 12;
        int ks = (idx >> 9) & 7;
        int lane = (idx >> 3) & 63;
        int j = idx & 7;
        int qq = lane >> 4, r16 = lane & 15;
        int k = ks * 32 + qq * 8 + j;
        int c = tt * 16 + r16;
        const float* Wl = sel ? W2l : W1l;
        const float* Wr = sel ? W2r : W1r;
        float v = (k < 128) ? Wl[k * 128 + c] : Wr[(k - 128) * 128 + c];
        unsigned int h = f2bf_bits(v);
        float hf = __uint_as_float(h << 16);
        unsigned int l = f2bf_bits(v - hf);
        (sel ? h2 : h1)[idx] = (unsigned short)h;
        (sel ? l2 : l1)[idx] = (unsigned short)l;
    } else {
        chist[t] = 0;
        if (t < 16) csrpad[t] = 0;
    }
}

// ---------------- pass A: coarse histogram (bucket = dst>>8) via LDS ----------------
__global__ __launch_bounds__(256) void coarse_count_kernel(const int* __restrict__ dst,
                                                           int* __restrict__ chist, int E) {
    __shared__ int h[256];
    h[threadIdx.x] = 0;
    __syncthreads();
    const int stride = gridDim.x * 256;
    for (int e = blockIdx.x * 256 + threadIdx.x; e < E; e += stride)
        atomicAdd(&h[dst[e] >> 8], 1);
    __syncthreads();
    int v = h[threadIdx.x];
    if (v) atomicAdd(&chist[threadIdx.x], v);
}

// ---------------- pass B: scan 256 bucket counts -> cbase (excl, 257) + gcur ----------------
__global__ __launch_bounds__(256) void scan256_kernel(const int* __restrict__ chist,
                                                      int* __restrict__ cbase,
                                                      int* __restrict__ gcur) {
    __shared__ int wsum[4];
    const int t = threadIdx.x, lane = t & 63, wv = t >> 6;
    int v = chist[t];
    int s = v;
#pragma unroll
    for (int o = 1; o < 64; o <<= 1) {
        int u = __shfl_up(s, o, 64);
        if (lane >= o) s += u;
    }
    if (lane == 63) wsum[wv] = s;
    __syncthreads();
    int add = 0;
    for (int w = 0; w < wv; ++w) add += wsum[w];
    cbase[t + 1] = s + add;
    if (t == 0) cbase[0] = 0;
    gcur[t] = s + add - v;
}

// ---------------- pass C: coarse multisplit scatter ----------------
#define CCHUNK 4096
__global__ __launch_bounds__(256) void coarse_scatter_kernel(
    const int* __restrict__ src, const int* __restrict__ dst,
    int* __restrict__ gcur, unsigned int* __restrict__ centries, int E)
{
    __shared__ int h[256];
    __shared__ int base[256];
    __shared__ unsigned int stage[CCHUNK];
    const int t = threadIdx.x;
    const int e0 = blockIdx.x * CCHUNK;
    h[t] = 0;
    __syncthreads();
#pragma unroll
    for (int i = 0; i < 16; ++i) {
        int e = e0 + i * 256 + t;
        unsigned int u = 0xFFFFFFFFu;
        if (e < E) {
            int d = dst[e];
            int s = src[e];
            int b = d >> 8;
            u = ((unsigned)b << 24) | ((unsigned)s << 8) | (unsigned)(d & 255);
            atomicAdd(&h[b], 1);
        }
        stage[i * 256 + t] = u;
    }
    __syncthreads();
    base[t] = atomicAdd(&gcur[t], h[t]);
    __syncthreads();
    h[t] = 0;
    __syncthreads();
#pragma unroll
    for (int i = 0; i < 16; ++i) {
        unsigned int u = stage[i * 256 + t];
        if (u != 0xFFFFFFFFu) {
            int b = u >> 24;
            int r = atomicAdd(&h[b], 1);
            centries[base[b] + r] = u & 0x00FFFFFFu;
        }
    }
}

// ---------------- pass D: fine bucket (one block per coarse bucket) ----------------
#define DCAP 8192
__global__ __launch_bounds__(256) void fine_bucket_kernel(
    const unsigned int* __restrict__ centries,
    const int* __restrict__ cbase,
    int* __restrict__ offo, int* __restrict__ csr, int N, int E)
{
    __shared__ int h[256], ex[256], wsum[4];
    __shared__ int stg[DCAP];
    const int t = threadIdx.x, lane = t & 63, wv = t >> 6;
    const int b = blockIdx.x;
    const int s0 = cbase[b];
    const int cnt = cbase[b + 1] - s0;
    h[t] = 0;
    __syncthreads();
    for (int i = t; i < cnt; i += 256)
        atomicAdd(&h[centries[s0 + i] & 255], 1);
    __syncthreads();
    int v = h[t], s = v;
#pragma unroll
    for (int o = 1; o < 64; o <<= 1) {
        int u = __shfl_up(s, o, 64);
        if (lane >= o) s += u;
    }
    if (lane == 63) wsum[wv] = s;
    __syncthreads();
    int add = 0;
    for (int w = 0; w < wv; ++w) add += wsum[w];
    const int exc = s + add - v;
    ex[t] = exc;
    const int dg = b * 256 + t;
    if (dg < N) offo[dg] = s0 + exc;
    if (b == 0 && t == 0) offo[N] = E;
    h[t] = 0;
    __syncthreads();
    if (cnt <= DCAP) {
        for (int i = t; i < cnt; i += 256) {
            unsigned int u = centries[s0 + i];
            int dl = u & 255;
            int r = atomicAdd(&h[dl], 1);
            stg[ex[dl] + r] = (int)(u >> 8);
        }
        __syncthreads();
        for (int i = t; i < cnt; i += 256)
            csr[s0 + i] = stg[i];
    } else {
        for (int i = t; i < cnt; i += 256) {
            unsigned int u = centries[s0 + i];
            int dl = u & 255;
            int r = atomicAdd(&h[dl], 1);
            csr[s0 + ex[dl] + r] = (int)(u >> 8);
        }
    }
}

// ---------------- gather-mean (bf16 table -> packed A-frag bf16 hi/lo) ----------------
// 16 lanes per node; lane covers 8 channels (16 B loads). 16-deep masked batches
// (CSR padded by 16; overshoot reads neighbor-node edges = harmless prefetch).
__global__ __launch_bounds__(256) void gather_mean_kernel(
    const unsigned short* __restrict__ featbf,
    const int* __restrict__ off,
    const int* __restrict__ csr,
    unsigned short* __restrict__ agg_hi,
    unsigned short* __restrict__ agg_lo,
    int n_nodes)
{
    const int hw = (blockIdx.x * 256 + threadIdx.x) >> 4;   // node id
    const int L = threadIdx.x & 15;
    if (hw >= n_nodes) return;
    const unsigned short* fb = featbf + (size_t)L * 8;
    const int start = off[hw];
    const int end = off[hw + 1];
    float acc[8] = {0.f, 0.f, 0.f, 0.f, 0.f, 0.f, 0.f, 0.f};
    for (int e = start; e < end; e += 16) {
        int4 ia = *(const int4*)(csr + e);
        int4 ib = *(const int4*)(csr + e + 4);
        int4 ic = *(const int4*)(csr + e + 8);
        int4 id = *(const int4*)(csr + e + 12);
        uint4 r[16];
        r[0]  = *(const uint4*)(fb + (size_t)ia.x * D);
        r[1]  = *(const uint4*)(fb + (size_t)ia.y * D);
        r[2]  = *(const uint4*)(fb + (size_t)ia.z * D);
        r[3]  = *(const uint4*)(fb + (size_t)ia.w * D);
        r[4]  = *(const uint4*)(fb + (size_t)ib.x * D);
        r[5]  = *(const uint4*)(fb + (size_t)ib.y * D);
        r[6]  = *(const uint4*)(fb + (size_t)ib.z * D);
        r[7]  = *(const uint4*)(fb + (size_t)ib.w * D);
        r[8]  = *(const uint4*)(fb + (size_t)ic.x * D);
        r[9]  = *(const uint4*)(fb + (size_t)ic.y * D);
        r[10] = *(const uint4*)(fb + (size_t)ic.z * D);
        r[11] = *(const uint4*)(fb + (size_t)ic.w * D);
        r[12] = *(const uint4*)(fb + (size_t)id.x * D);
        r[13] = *(const uint4*)(fb + (size_t)id.y * D);
        r[14] = *(const uint4*)(fb + (size_t)id.z * D);
        r[15] = *(const uint4*)(fb + (size_t)id.w * D);
#pragma unroll
        for (int p = 0; p < 16; ++p) {
            uint4 rv = r[p];
            if (e + p >= end) { rv.x = 0u; rv.y = 0u; rv.z = 0u; rv.w = 0u; }
            acc[0] += bfhi(rv.x); acc[1] += bflo(rv.x);
            acc[2] += bfhi(rv.y); acc[3] += bflo(rv.y);
            acc[4] += bfhi(rv.z); acc[5] += bflo(rv.z);
            acc[6] += bfhi(rv.w); acc[7] += bflo(rv.w);
        }
    }
    const float dinv = 1.0f / (float)max(end - start, 1);
    short8 hi8, lo8;
#pragma unroll
    for (int i = 0; i < 8; ++i) {
        float v = acc[i] * dinv;
        unsigned int h = f2bf_bits(v);
        float hf = __uint_as_float(h << 16);
        hi8[i] = (short)h;
        lo8[i] = (short)f2bf_bits(v - hf);
    }
    // packed A-frag store: lane L holds k = L*8 + i  ->  ks = L>>2, q = L&3
    const int tile = hw >> 4, r16 = hw & 15;
    const int ks = L >> 2, qq = L & 3;
    const size_t p = ((size_t)(tile * 4 + ks) * 64 + qq * 16 + r16) * 8;
    *(short8*)(agg_hi + p) = hi8;
    *(short8*)(agg_lo + p) = lo8;
}

// ---------------- dense MFMA GEMM: out = agg@Wl + self@Wr + b ----------------
// All A operands pre-split bf16 hi/lo: packed frags for agg (ks<4),
// row-major (stride D) for self (ks>=4). Zero f2bf work in the k-loop.
__global__ __launch_bounds__(256) void sage_gemm_kernel(
    const unsigned short* __restrict__ agg_hi,
    const unsigned short* __restrict__ agg_lo,
    const unsigned short* __restrict__ self_hi,   // row-major bf16 (hi)
    const unsigned short* __restrict__ self_lo,   // row-major bf16 (lo)
    const unsigned short* __restrict__ wpk_hi,
    const unsigned short* __restrict__ wpk_lo,
    const float* __restrict__ bias,
    unsigned short* __restrict__ out_hi,          // row-major bf16
    unsigned short* __restrict__ out_lo,          // nullable (layer-1 h lo)
    int ntiles, int do_relu)
{
    const int wv = threadIdx.x >> 6;
    const int lane = threadIdx.x & 63;
    const int tile = blockIdx.x * 4 + wv;
    if (tile >= ntiles) return;
    const int q = lane >> 4, r16 = lane & 15;
    const int n0w = tile * 16;

    f32x4 acc8[8];
#pragma unroll
    for (int t = 0; t < 8; ++t) acc8[t] = (f32x4){0.f, 0.f, 0.f, 0.f};

    const unsigned short* aph = agg_hi + (size_t)tile * 2048 + lane * 8;
    const unsigned short* apl = agg_lo + (size_t)tile * 2048 + lane * 8;
    const unsigned short* sph = self_hi + (size_t)(n0w + r16) * D + q * 8;
    const unsigned short* spl = self_lo + (size_t)(n0w + r16) * D + q * 8;

    for (int ks = 0; ks < 8; ++ks) {
        short8 ahi, alo;
        if (ks < 4) {
            ahi = *(const short8*)(aph + ks * 512);
            alo = *(const short8*)(apl + ks * 512);
        } else {
            ahi = *(const short8*)(sph + (ks - 4) * 32);
            alo = *(const short8*)(spl + (ks - 4) * 32);
        }
        short8 BH[8], BL[8];
        const unsigned short* bh = wpk_hi + (size_t)ks * 512 + lane * 8;
        const unsigned short* bl = wpk_lo + (size_t)ks * 512 + lane * 8;
#pragma unroll
        for (int t = 0; t < 8; ++t) {
            BH[t] = *(const short8*)(bh + (size_t)t * 4096);
            BL[t] = *(const short8*)(bl + (size_t)t * 4096);
        }
#pragma unroll
        for (int t = 0; t < 8; ++t) {
            acc8[t] = __builtin_amdgcn_mfma_f32_16x16x32_bf16(ahi, BH[t], acc8[t], 0, 0, 0);
            acc8[t] = __builtin_amdgcn_mfma_f32_16x16x32_bf16(alo, BH[t], acc8[t], 0, 0, 0);
            acc8[t] = __builtin_amdgcn_mfma_f32_16x16x32_bf16(ahi, BL[t], acc8[t], 0, 0, 0);
        }
    }

    // epilogue: C/D layout col=lane&15, row=quad*4+reg; row-major bf16 out
#pragma unroll
    for (int t = 0; t < 8; ++t) {
        const float bv = bias[t * 16 + r16];
#pragma unroll
        for (int r = 0; r < 4; ++r) {
            float vv = acc8[t][r] + bv;
            if (do_relu) vv = fmaxf(vv, 0.f);
            const size_t o = (size_t)(n0w + q * 4 + r) * D + t * 16 + r16;
            unsigned int h = f2bf_bits(vv);
            out_hi[o] = (unsigned short)h;
            if (out_lo) {
                float hf = __uint_as_float(h << 16);
                out_lo[o] = (unsigned short)f2bf_bits(vv - hf);
            }
        }
    }
}

// ---------------- edge dot-product decode (bf16 z rows) ----------------
// 16 lanes per edge, 16 B loads, reduce depth 4.
__global__ __launch_bounds__(256) void pred_kernel(const unsigned short* __restrict__ zbf,
                                                   const int* __restrict__ ps,
                                                   const int* __restrict__ pd,
                                                   float* __restrict__ out, int EP) {
    int idx = blockIdx.x * 256 + threadIdx.x;
    int e = idx >> 4;
    if (e >= EP) return;
    int L = idx & 15;
    const unsigned short* fb = zbf + (size_t)L * 8;
    uint4 ra = *(const uint4*)(fb + (size_t)ps[e] * D);
    uint4 rb = *(const uint4*)(fb + (size_t)pd[e] * D);
    float p = bfhi(ra.x) * bfhi(rb.x) + bflo(ra.x) * bflo(rb.x)
            + bfhi(ra.y) * bfhi(rb.y) + bflo(ra.y) * bflo(rb.y)
            + bfhi(ra.z) * bfhi(rb.z) + bflo(ra.z) * bflo(rb.z)
            + bfhi(ra.w) * bfhi(rb.w) + bflo(ra.w) * bflo(rb.w);
#pragma unroll
    for (int off = 8; off > 0; off >>= 1) p += __shfl_xor(p, off, 16);
    if (L == 0) out[e] = p;
}

extern "C" void kernel_launch(void* const* d_in, const int* in_sizes, int n_in,
                              void* d_out, int out_size, void* d_ws, size_t ws_size,
                              hipStream_t stream) {
    const float* x   = (const float*)d_in[0];
    const float* W1l = (const float*)d_in[1];
    const float* b1  = (const float*)d_in[2];
    const float* W1r = (const float*)d_in[3];
    const float* W2l = (const float*)d_in[4];
    const float* b2  = (const float*)d_in[5];
    const float* W2r = (const float*)d_in[6];
    const int* edge_index = (const int*)d_in[7];
    const int* pred_edges = (const int*)d_in[8];
    float* out = (float*)d_out;

    const int N  = in_sizes[0] / D;   // 50000
    const int E  = in_sizes[7] / 2;   // 800000
    const int EP = in_sizes[8] / 2;   // 200000

    const int* src = edge_index;
    const int* dst = edge_index + E;
    const int* ps  = pred_edges;
    const int* pd  = pred_edges + EP;

    // workspace layout
    int* chist   = (int*)d_ws;                 // 256
    int* cbase   = chist + 256;                // 257 (pad 272)
    int* gcur    = cbase + 272;                // 256
    int* off     = gcur + 256;                 // N+1 (pad 50016)
    unsigned int* centries = (unsigned int*)(off + 50016);  // E
    int* csr     = (int*)(centries + E);       // E + 16 pad
    unsigned short* w1_hi = (unsigned short*)(csr + E + 16);
    unsigned short* w1_lo = w1_hi + 32768;
    unsigned short* w2_hi = w1_lo + 32768;
    unsigned short* w2_lo = w2_hi + 32768;
    unsigned short* xbf   = w2_lo + 32768;          // N*D bf16 (x hi, gather-1 table)
    unsigned short* xlo   = xbf + (size_t)N * D;    // N*D bf16 (x lo)
    unsigned short* hbf   = xlo + (size_t)N * D;    // N*D bf16 (h hi, gather-2 table)
    unsigned short* hlo   = hbf + (size_t)N * D;    // N*D bf16 (h lo)
    unsigned short* zbf   = hlo + (size_t)N * D;    // N*D bf16 (z)
    unsigned short* agg_hi = zbf + (size_t)N * D;   // N*D bf16 packed frags
    unsigned short* agg_lo = agg_hi + (size_t)N * D;

    const int n4 = N * D / 4;
    const int ncast = (n4 + 255) / 256;             // 6250
    const int nblk_gather = (N * 16 + 255) / 256;   // 3125
    const int ntiles = N / 16;                      // 3125
    const int nblk_gemm = (ntiles + 3) / 4;         // 782
    const int nbC = (E + CCHUNK - 1) / CCHUNK;      // 196
    const int nbD = (N + 255) / 256;                // 196
    const int nblk_pred = (EP * 16 + 255) / 256;    // 12500

    // fused prep: x hi/lo cast + weight pack + zero chist & csr pad
    prep_kernel<<<ncast + 257, 256, 0, stream>>>(x, W1l, W1r, W2l, W2r,
                                                 xbf, xlo, w1_hi, w1_lo, w2_hi, w2_lo,
                                                 n4, ncast, chist, csr + E);

    // CSR build: coarse count -> scan -> coarse multisplit -> fine bucket
    coarse_count_kernel<<<256, 256, 0, stream>>>(dst, chist, E);
    scan256_kernel<<<1, 256, 0, stream>>>(chist, cbase, gcur);
    coarse_scatter_kernel<<<nbC, 256, 0, stream>>>(src, dst, gcur, centries, E);
    fine_bucket_kernel<<<nbD, 256, 0, stream>>>(centries, cbase, off, csr, N, E);

    // layer 1: h = relu(mean(x)@W1l + x@W1r + b1) -> hbf/hlo (row bf16 hi/lo)
    gather_mean_kernel<<<nblk_gather, 256, 0, stream>>>(xbf, off, csr, agg_hi, agg_lo, N);
    sage_gemm_kernel<<<nblk_gemm, 256, 0, stream>>>(agg_hi, agg_lo, xbf, xlo,
                                                    w1_hi, w1_lo, b1, hbf, hlo, ntiles, 1);
    // layer 2: z = mean(h)@W2l + h@W2r + b2 -> zbf (row bf16)
    gather_mean_kernel<<<nblk_gather, 256, 0, stream>>>(hbf, off, csr, agg_hi, agg_lo, N);
    sage_gemm_kernel<<<nblk_gemm, 256, 0, stream>>>(agg_hi, agg_lo, hbf, hlo,
                                                    w2_hi, w2_lo, b2, zbf, (unsigned short*)nullptr,
                                                    ntiles, 0);
    // decode from bf16 z
    pred_kernel<<<nblk_pred, 256, 0, stream>>>(zbf, ps, pd, out, EP);
}

// Round 2
// 276.016 us; speedup vs baseline: 1.1256x; 1.1256x over previous
//
#include <hip/hip_runtime.h>

#define D 128

typedef __attribute__((ext_vector_type(8))) short short8;
typedef __attribute__((ext_vector_type(4))) float f32x4;

// fp32 -> bf16 bits, round-to-nearest-even
__device__ inline unsigned int f2bf_bits(float f) {
    unsigned int u = __float_as_uint(f);
    return (u + 0x7FFFu + ((u >> 16) & 1u)) >> 16;
}

__device__ inline float bfhi(unsigned int u) { return __uint_as_float(u << 16); }
__device__ inline float bflo(unsigned int u) { return __uint_as_float(u & 0xffff0000u); }

// ---------------- fused prep: x -> bf16 hi/lo (row-major), weight pack, zero chist/csrpad ----
__global__ __launch_bounds__(256) void prep_kernel(
    const float* __restrict__ x,
    const float* __restrict__ W1l, const float* __restrict__ W1r,
    const float* __restrict__ W2l, const float* __restrict__ W2r,
    unsigned short* __restrict__ xbf, unsigned short* __restrict__ xlo,
    unsigned short* __restrict__ h1, unsigned short* __restrict__ l1,
    unsigned short* __restrict__ h2, unsigned short* __restrict__ l2,
    int n4, int ncast, int* __restrict__ chist, int* __restrict__ csrpad)
{
    const int b = blockIdx.x;
    const int t = threadIdx.x;
    if (b < ncast) {
        int i = b * 256 + t;
        if (i >= n4) return;
        f32x4 v = *(const f32x4*)(x + (size_t)i * 4);
        ushort4 oh, ol;
        {
            unsigned int h; float hf;
            h = f2bf_bits(v.x); hf = __uint_as_float(h << 16);
            oh.x = (unsigned short)h; ol.x = (unsigned short)f2bf_bits(v.x - hf);
            h = f2bf_bits(v.y); hf = __uint_as_float(h << 16);
            oh.y = (unsigned short)h; ol.y = (unsigned short)f2bf_bits(v.y - hf);
            h = f2bf_bits(v.z); hf = __uint_as_float(h << 16);
            oh.z = (unsigned short)h; ol.z = (unsigned short)f2bf_bits(v.z - hf);
            h = f2bf_bits(v.w); hf = __uint_as_float(h << 16);
            oh.w = (unsigned short)h; ol.w = (unsigned short)f2bf_bits(v.w - hf);
        }
        *(ushort4*)(xbf + (size_t)i * 4) = oh;
        *(ushort4*)(xlo + (size_t)i * 4) = ol;
    } else if (b < ncast + 256) {
        // weight pack: B-frag order + bf16 hi/lo split
        int gidx = (b - ncast) * 256 + t;   // 0..65535
        int sel = gidx >> 15;
        int idx = gidx & 32767;
        int tt = idx >> 12;
        int ks = (idx >> 9) & 7;
        int lane = (idx >> 3) & 63;
        int j = idx & 7;
        int qq = lane >> 4, r16 = lane & 15;
        int k = ks * 32 + qq * 8 + j;
        int c = tt * 16 + r16;
        const float* Wl = sel ? W2l : W1l;
        const float* Wr = sel ? W2r : W1r;
        float v = (k < 128) ? Wl[k * 128 + c] : Wr[(k - 128) * 128 + c];
        unsigned int h = f2bf_bits(v);
        float hf = __uint_as_float(h << 16);
        unsigned int l = f2bf_bits(v - hf);
        (sel ? h2 : h1)[idx] = (unsigned short)h;
        (sel ? l2 : l1)[idx] = (unsigned short)l;
    } else {
        chist[t] = 0;
        if (t < 16) csrpad[t] = 0;
    }
}

// ---------------- pass A: coarse histogram (bucket = dst>>8) via LDS ----------------
__global__ __launch_bounds__(256) void coarse_count_kernel(const int* __restrict__ dst,
                                                           int* __restrict__ chist, int E) {
    __shared__ int h[256];
    h[threadIdx.x] = 0;
    __syncthreads();
    const int stride = gridDim.x * 256;
    for (int e = blockIdx.x * 256 + threadIdx.x; e < E; e += stride)
        atomicAdd(&h[dst[e] >> 8], 1);
    __syncthreads();
    int v = h[threadIdx.x];
    if (v) atomicAdd(&chist[threadIdx.x], v);
}

// ---------------- pass B: scan 256 bucket counts -> cbase (excl, 257) + gcur ----------------
__global__ __launch_bounds__(256) void scan256_kernel(const int* __restrict__ chist,
                                                      int* __restrict__ cbase,
                                                      int* __restrict__ gcur) {
    __shared__ int wsum[4];
    const int t = threadIdx.x, lane = t & 63, wv = t >> 6;
    int v = chist[t];
    int s = v;
#pragma unroll
    for (int o = 1; o < 64; o <<= 1) {
        int u = __shfl_up(s, o, 64);
        if (lane >= o) s += u;
    }
    if (lane == 63) wsum[wv] = s;
    __syncthreads();
    int add = 0;
    for (int w = 0; w < wv; ++w) add += wsum[w];
    cbase[t + 1] = s + add;
    if (t == 0) cbase[0] = 0;
    gcur[t] = s + add - v;
}

// ---------------- pass C: coarse multisplit scatter ----------------
#define CCHUNK 4096
__global__ __launch_bounds__(256) void coarse_scatter_kernel(
    const int* __restrict__ src, const int* __restrict__ dst,
    int* __restrict__ gcur, unsigned int* __restrict__ centries, int E)
{
    __shared__ int h[256];
    __shared__ int base[256];
    __shared__ unsigned int stage[CCHUNK];
    const int t = threadIdx.x;
    const int e0 = blockIdx.x * CCHUNK;
    h[t] = 0;
    __syncthreads();
#pragma unroll
    for (int i = 0; i < 16; ++i) {
        int e = e0 + i * 256 + t;
        unsigned int u = 0xFFFFFFFFu;
        if (e < E) {
            int d = dst[e];
            int s = src[e];
            int b = d >> 8;
            u = ((unsigned)b << 24) | ((unsigned)s << 8) | (unsigned)(d & 255);
            atomicAdd(&h[b], 1);
        }
        stage[i * 256 + t] = u;
    }
    __syncthreads();
    base[t] = atomicAdd(&gcur[t], h[t]);
    __syncthreads();
    h[t] = 0;
    __syncthreads();
#pragma unroll
    for (int i = 0; i < 16; ++i) {
        unsigned int u = stage[i * 256 + t];
        if (u != 0xFFFFFFFFu) {
            int b = u >> 24;
            int r = atomicAdd(&h[b], 1);
            centries[base[b] + r] = u & 0x00FFFFFFu;
        }
    }
}

// ---------------- pass D: fine bucket (one block per coarse bucket) ----------------
#define DCAP 8192
__global__ __launch_bounds__(256) void fine_bucket_kernel(
    const unsigned int* __restrict__ centries,
    const int* __restrict__ cbase,
    int* __restrict__ offo, int* __restrict__ csr, int N, int E)
{
    __shared__ int h[256], ex[256], wsum[4];
    __shared__ int stg[DCAP];
    const int t = threadIdx.x, lane = t & 63, wv = t >> 6;
    const int b = blockIdx.x;
    const int s0 = cbase[b];
    const int cnt = cbase[b + 1] - s0;
    h[t] = 0;
    __syncthreads();
    for (int i = t; i < cnt; i += 256)
        atomicAdd(&h[centries[s0 + i] & 255], 1);
    __syncthreads();
    int v = h[t], s = v;
#pragma unroll
    for (int o = 1; o < 64; o <<= 1) {
        int u = __shfl_up(s, o, 64);
        if (lane >= o) s += u;
    }
    if (lane == 63) wsum[wv] = s;
    __syncthreads();
    int add = 0;
    for (int w = 0; w < wv; ++w) add += wsum[w];
    const int exc = s + add - v;
    ex[t] = exc;
    const int dg = b * 256 + t;
    if (dg < N) offo[dg] = s0 + exc;
    if (b == 0 && t == 0) offo[N] = E;
    h[t] = 0;
    __syncthreads();
    if (cnt <= DCAP) {
        for (int i = t; i < cnt; i += 256) {
            unsigned int u = centries[s0 + i];
            int dl = u & 255;
            int r = atomicAdd(&h[dl], 1);
            stg[ex[dl] + r] = (int)(u >> 8);
        }
        __syncthreads();
        for (int i = t; i < cnt; i += 256)
            csr[s0 + i] = stg[i];
    } else {
        for (int i = t; i < cnt; i += 256) {
            unsigned int u = centries[s0 + i];
            int dl = u & 255;
            int r = atomicAdd(&h[dl], 1);
            csr[s0 + ex[dl] + r] = (int)(u >> 8);
        }
    }
}

// ---------------- gather-mean (bf16 table -> packed A-frag bf16 hi/lo) ----------------
// Round-0 structure: half-wave (32 lanes) per node; lane covers 4 channels (8 B loads).
// Masked 16-deep batches (CSR padded by 16). Emits pre-split bf16 hi/lo frags.
__global__ __launch_bounds__(256) void gather_mean_kernel(
    const unsigned short* __restrict__ featbf,
    const int* __restrict__ off,
    const int* __restrict__ csr,
    unsigned short* __restrict__ agg_hi,
    unsigned short* __restrict__ agg_lo,
    int n_nodes)
{
    const int hw = (blockIdx.x * 256 + threadIdx.x) >> 5;   // node id
    const int l5 = threadIdx.x & 31;
    if (hw >= n_nodes) return;
    const unsigned short* fb = featbf + (size_t)l5 * 4;
    const int start = off[hw];
    const int end = off[hw + 1];
    f32x4 acc = {0.f, 0.f, 0.f, 0.f};
    for (int e = start; e < end; e += 16) {
        int4 ia = *(const int4*)(csr + e);
        int4 ib = *(const int4*)(csr + e + 4);
        int4 ic = *(const int4*)(csr + e + 8);
        int4 id = *(const int4*)(csr + e + 12);
        uint2 r[16];
        r[0]  = *(const uint2*)(fb + (size_t)ia.x * D);
        r[1]  = *(const uint2*)(fb + (size_t)ia.y * D);
        r[2]  = *(const uint2*)(fb + (size_t)ia.z * D);
        r[3]  = *(const uint2*)(fb + (size_t)ia.w * D);
        r[4]  = *(const uint2*)(fb + (size_t)ib.x * D);
        r[5]  = *(const uint2*)(fb + (size_t)ib.y * D);
        r[6]  = *(const uint2*)(fb + (size_t)ib.z * D);
        r[7]  = *(const uint2*)(fb + (size_t)ib.w * D);
        r[8]  = *(const uint2*)(fb + (size_t)ic.x * D);
        r[9]  = *(const uint2*)(fb + (size_t)ic.y * D);
        r[10] = *(const uint2*)(fb + (size_t)ic.z * D);
        r[11] = *(const uint2*)(fb + (size_t)ic.w * D);
        r[12] = *(const uint2*)(fb + (size_t)id.x * D);
        r[13] = *(const uint2*)(fb + (size_t)id.y * D);
        r[14] = *(const uint2*)(fb + (size_t)id.z * D);
        r[15] = *(const uint2*)(fb + (size_t)id.w * D);
#pragma unroll
        for (int p = 0; p < 16; ++p) {
            uint2 rv = r[p];
            if (e + p >= end) { rv.x = 0u; rv.y = 0u; }
            acc.x += __uint_as_float(rv.x << 16);
            acc.y += __uint_as_float(rv.x & 0xffff0000u);
            acc.z += __uint_as_float(rv.y << 16);
            acc.w += __uint_as_float(rv.y & 0xffff0000u);
        }
    }
    float dinv = 1.0f / (float)max(end - start, 1);
    acc *= dinv;
    // packed A-frag hi/lo store: k = l5*4 + i
    const int tile = hw >> 4, r16 = hw & 15;
    const int ks = l5 >> 3, qc = (l5 & 7) >> 1, jb = (l5 & 1) * 4;
    const size_t p = ((size_t)(tile * 4 + ks) * 64 + qc * 16 + r16) * 8 + jb;
    ushort4 oh, ol;
#pragma unroll
    for (int i = 0; i < 4; ++i) {
        float v = acc[i];
        unsigned int h = f2bf_bits(v);
        float hf = __uint_as_float(h << 16);
        ((unsigned short*)&oh)[i] = (unsigned short)h;
        ((unsigned short*)&ol)[i] = (unsigned short)f2bf_bits(v - hf);
    }
    *(ushort4*)(agg_hi + p) = oh;
    *(ushort4*)(agg_lo + p) = ol;
}

// ---------------- dense MFMA GEMM: out = agg@Wl + self@Wr + b ----------------
// Pre-split bf16 A, explicit depth-2 register double-buffer: B/A loads for
// iteration ks+1 are issued BEFORE the MFMA cluster of ks, so the compiler
// emits counted vmcnt waits and MFMA overlaps the in-flight loads.
__device__ inline void loadb8(const unsigned short* __restrict__ bh,
                              const unsigned short* __restrict__ bl,
                              int ks, short8* BH, short8* BL) {
    const unsigned short* p = bh + (size_t)ks * 512;
    const unsigned short* q = bl + (size_t)ks * 512;
#pragma unroll
    for (int t = 0; t < 8; ++t) {
        BH[t] = *(const short8*)(p + (size_t)t * 4096);
        BL[t] = *(const short8*)(q + (size_t)t * 4096);
    }
}

__device__ inline void mfma24(const short8& AH, const short8& AL,
                              const short8* BH, const short8* BL, f32x4* acc) {
#pragma unroll
    for (int t = 0; t < 8; ++t) {
        acc[t] = __builtin_amdgcn_mfma_f32_16x16x32_bf16(AH, BH[t], acc[t], 0, 0, 0);
        acc[t] = __builtin_amdgcn_mfma_f32_16x16x32_bf16(AL, BH[t], acc[t], 0, 0, 0);
        acc[t] = __builtin_amdgcn_mfma_f32_16x16x32_bf16(AH, BL[t], acc[t], 0, 0, 0);
    }
}

__global__ __launch_bounds__(256, 2) void sage_gemm_kernel(
    const unsigned short* __restrict__ agg_hi,
    const unsigned short* __restrict__ agg_lo,
    const unsigned short* __restrict__ self_hi,   // row-major bf16 (hi)
    const unsigned short* __restrict__ self_lo,   // row-major bf16 (lo)
    const unsigned short* __restrict__ wpk_hi,
    const unsigned short* __restrict__ wpk_lo,
    const float* __restrict__ bias,
    unsigned short* __restrict__ out_hi,          // row-major bf16
    unsigned short* __restrict__ out_lo,          // nullable (layer-1 h lo)
    int ntiles, int do_relu)
{
    const int wv = threadIdx.x >> 6;
    const int lane = threadIdx.x & 63;
    const int tile = blockIdx.x * 4 + wv;
    if (tile >= ntiles) return;
    const int q = lane >> 4, r16 = lane & 15;
    const int n0w = tile * 16;

    f32x4 acc8[8];
#pragma unroll
    for (int t = 0; t < 8; ++t) acc8[t] = (f32x4){0.f, 0.f, 0.f, 0.f};

    const unsigned short* aph = agg_hi + (size_t)tile * 2048 + lane * 8;
    const unsigned short* apl = agg_lo + (size_t)tile * 2048 + lane * 8;
    const unsigned short* sph = self_hi + (size_t)(n0w + r16) * D + q * 8;
    const unsigned short* spl = self_lo + (size_t)(n0w + r16) * D + q * 8;
    const unsigned short* bh  = wpk_hi + lane * 8;
    const unsigned short* bl  = wpk_lo + lane * 8;

#define LOADA(ks, AH, AL)                                           \
    if ((ks) < 4) {                                                 \
        AH = *(const short8*)(aph + (ks) * 512);                    \
        AL = *(const short8*)(apl + (ks) * 512);                    \
    } else {                                                        \
        AH = *(const short8*)(sph + ((ks) - 4) * 32);               \
        AL = *(const short8*)(spl + ((ks) - 4) * 32);               \
    }

    short8 BH0[8], BL0[8], BH1[8], BL1[8];
    short8 AH0, AL0, AH1, AL1;

    loadb8(bh, bl, 0, BH0, BL0); LOADA(0, AH0, AL0);
    loadb8(bh, bl, 1, BH1, BL1); LOADA(1, AH1, AL1);
    mfma24(AH0, AL0, BH0, BL0, acc8);
    loadb8(bh, bl, 2, BH0, BL0); LOADA(2, AH0, AL0);
    mfma24(AH1, AL1, BH1, BL1, acc8);
    loadb8(bh, bl, 3, BH1, BL1); LOADA(3, AH1, AL1);
    mfma24(AH0, AL0, BH0, BL0, acc8);
    loadb8(bh, bl, 4, BH0, BL0); LOADA(4, AH0, AL0);
    mfma24(AH1, AL1, BH1, BL1, acc8);
    loadb8(bh, bl, 5, BH1, BL1); LOADA(5, AH1, AL1);
    mfma24(AH0, AL0, BH0, BL0, acc8);
    loadb8(bh, bl, 6, BH0, BL0); LOADA(6, AH0, AL0);
    mfma24(AH1, AL1, BH1, BL1, acc8);
    loadb8(bh, bl, 7, BH1, BL1); LOADA(7, AH1, AL1);
    mfma24(AH0, AL0, BH0, BL0, acc8);
    mfma24(AH1, AL1, BH1, BL1, acc8);
#undef LOADA

    // epilogue: C/D layout col=lane&15, row=quad*4+reg; row-major bf16 out
#pragma unroll
    for (int t = 0; t < 8; ++t) {
        const float bv = bias[t * 16 + r16];
#pragma unroll
        for (int r = 0; r < 4; ++r) {
            float vv = acc8[t][r] + bv;
            if (do_relu) vv = fmaxf(vv, 0.f);
            const size_t o = (size_t)(n0w + q * 4 + r) * D + t * 16 + r16;
            unsigned int h = f2bf_bits(vv);
            out_hi[o] = (unsigned short)h;
            if (out_lo) {
                float hf = __uint_as_float(h << 16);
                out_lo[o] = (unsigned short)f2bf_bits(vv - hf);
            }
        }
    }
}

// ---------------- edge dot-product decode (bf16 z rows) ----------------
// Round-0 structure: 32 lanes per edge, 8 B loads, reduce depth 5.
__global__ __launch_bounds__(256) void pred_kernel(const unsigned short* __restrict__ zbf,
                                                   const int* __restrict__ ps,
                                                   const int* __restrict__ pd,
                                                   float* __restrict__ out, int EP) {
    int idx = blockIdx.x * blockDim.x + threadIdx.x;
    int e = idx >> 5;
    if (e >= EP) return;
    int l = idx & 31;
    const unsigned short* fb = zbf + (size_t)l * 4;
    uint2 ra = *(const uint2*)(fb + (size_t)ps[e] * D);
    uint2 rb = *(const uint2*)(fb + (size_t)pd[e] * D);
    float p = __uint_as_float(ra.x << 16)         * __uint_as_float(rb.x << 16)
            + __uint_as_float(ra.x & 0xffff0000u) * __uint_as_float(rb.x & 0xffff0000u)
            + __uint_as_float(ra.y << 16)         * __uint_as_float(rb.y << 16)
            + __uint_as_float(ra.y & 0xffff0000u) * __uint_as_float(rb.y & 0xffff0000u);
#pragma unroll
    for (int off = 16; off > 0; off >>= 1) p += __shfl_xor(p, off, 32);
    if (l == 0) out[e] = p;
}

extern "C" void kernel_launch(void* const* d_in, const int* in_sizes, int n_in,
                              void* d_out, int out_size, void* d_ws, size_t ws_size,
                              hipStream_t stream) {
    const float* x   = (const float*)d_in[0];
    const float* W1l = (const float*)d_in[1];
    const float* b1  = (const float*)d_in[2];
    const float* W1r = (const float*)d_in[3];
    const float* W2l = (const float*)d_in[4];
    const float* b2  = (const float*)d_in[5];
    const float* W2r = (const float*)d_in[6];
    const int* edge_index = (const int*)d_in[7];
    const int* pred_edges = (const int*)d_in[8];
    float* out = (float*)d_out;

    const int N  = in_sizes[0] / D;   // 50000
    const int E  = in_sizes[7] / 2;   // 800000
    const int EP = in_sizes[8] / 2;   // 200000

    const int* src = edge_index;
    const int* dst = edge_index + E;
    const int* ps  = pred_edges;
    const int* pd  = pred_edges + EP;

    // workspace layout
    int* chist   = (int*)d_ws;                 // 256
    int* cbase   = chist + 256;                // 257 (pad 272)
    int* gcur    = cbase + 272;                // 256
    int* off     = gcur + 256;                 // N+1 (pad 50016)
    unsigned int* centries = (unsigned int*)(off + 50016);  // E
    int* csr     = (int*)(centries + E);       // E + 16 pad
    unsigned short* w1_hi = (unsigned short*)(csr + E + 16);
    unsigned short* w1_lo = w1_hi + 32768;
    unsigned short* w2_hi = w1_lo + 32768;
    unsigned short* w2_lo = w2_hi + 32768;
    unsigned short* xbf   = w2_lo + 32768;          // N*D bf16 (x hi, gather-1 table)
    unsigned short* xlo   = xbf + (size_t)N * D;    // N*D bf16 (x lo)
    unsigned short* hbf   = xlo + (size_t)N * D;    // N*D bf16 (h hi, gather-2 table)
    unsigned short* hlo   = hbf + (size_t)N * D;    // N*D bf16 (h lo)
    unsigned short* zbf   = hlo + (size_t)N * D;    // N*D bf16 (z)
    unsigned short* agg_hi = zbf + (size_t)N * D;   // N*D bf16 packed frags
    unsigned short* agg_lo = agg_hi + (size_t)N * D;

    const int n4 = N * D / 4;
    const int ncast = (n4 + 255) / 256;             // 6250
    const int nblk_gather = (N * 32 + 255) / 256;   // 6250
    const int ntiles = N / 16;                      // 3125
    const int nblk_gemm = (ntiles + 3) / 4;         // 782
    const int nbC = (E + CCHUNK - 1) / CCHUNK;      // 196
    const int nbD = (N + 255) / 256;                // 196
    const int nblk_pred = (EP * 32 + 255) / 256;    // 25000

    // fused prep: x hi/lo cast + weight pack + zero chist & csr pad
    prep_kernel<<<ncast + 257, 256, 0, stream>>>(x, W1l, W1r, W2l, W2r,
                                                 xbf, xlo, w1_hi, w1_lo, w2_hi, w2_lo,
                                                 n4, ncast, chist, csr + E);

    // CSR build: coarse count -> scan -> coarse multisplit -> fine bucket
    coarse_count_kernel<<<256, 256, 0, stream>>>(dst, chist, E);
    scan256_kernel<<<1, 256, 0, stream>>>(chist, cbase, gcur);
    coarse_scatter_kernel<<<nbC, 256, 0, stream>>>(src, dst, gcur, centries, E);
    fine_bucket_kernel<<<nbD, 256, 0, stream>>>(centries, cbase, off, csr, N, E);

    // layer 1: h = relu(mean(x)@W1l + x@W1r + b1) -> hbf/hlo (row bf16 hi/lo)
    gather_mean_kernel<<<nblk_gather, 256, 0, stream>>>(xbf, off, csr, agg_hi, agg_lo, N);
    sage_gemm_kernel<<<nblk_gemm, 256, 0, stream>>>(agg_hi, agg_lo, xbf, xlo,
                                                    w1_hi, w1_lo, b1, hbf, hlo, ntiles, 1);
    // layer 2: z = mean(h)@W2l + h@W2r + b2 -> zbf (row bf16)
    gather_mean_kernel<<<nblk_gather, 256, 0, stream>>>(hbf, off, csr, agg_hi, agg_lo, N);
    sage_gemm_kernel<<<nblk_gemm, 256, 0, stream>>>(agg_hi, agg_lo, hbf, hlo,
                                                    w2_hi, w2_lo, b2, zbf, (unsigned short*)nullptr,
                                                    ntiles, 0);
    // decode from bf16 z
    pred_kernel<<<nblk_pred, 256, 0, stream>>>(zbf, ps, pd, out, EP);
}